// Round 6
// baseline (3865.212 us; speedup 1.0000x reference)
//
#include <hip/hip_runtime.h>
#include <hip/hip_fp16.h>

#define K_DIM 32
#define BN 64               // nodes per bucket
#define MAXBUCK 2048        // LDS histogram capacity (N <= 131072)

__device__ __forceinline__ float tanh_fast(float x) {
    float e = __expf(2.0f * x);
    return 1.0f - 2.0f / (e + 1.0f);
}

// ---------------- bucket build ----------------

// coarse counts: per-block LDS histogram, one flush per (block, bucket)
__global__ void k_bcnt(const int* __restrict__ dst, int* __restrict__ bcnt,
                       int E, int nbuck) {
    __shared__ int h[MAXBUCK];
    for (int i = threadIdx.x; i < nbuck; i += blockDim.x) h[i] = 0;
    __syncthreads();
    for (int e = blockIdx.x * blockDim.x + threadIdx.x; e < E; e += gridDim.x * blockDim.x)
        atomicAdd(&h[dst[e] >> 6], 1);
    __syncthreads();
    for (int i = threadIdx.x; i < nbuck; i += blockDim.x)
        if (h[i]) atomicAdd(&bcnt[i], h[i]);
}

// single-block scan over nbuck counts -> boff[0..nbuck], gcur = boff
__global__ void k_bscan(const int* __restrict__ bcnt, int* __restrict__ boff,
                        int* __restrict__ gcur, int nbuck, int total) {
    __shared__ int sm[256];
    __shared__ int carry;
    int t = threadIdx.x;
    if (t == 0) carry = 0;
    __syncthreads();
    for (int base = 0; base < nbuck; base += 256) {
        int v = (base + t < nbuck) ? bcnt[base + t] : 0;
        sm[t] = v;
        __syncthreads();
        #pragma unroll
        for (int d = 1; d < 256; d <<= 1) {
            int tv = (t >= d) ? sm[t - d] : 0;
            __syncthreads();
            sm[t] += tv;
            __syncthreads();
        }
        int excl = carry + sm[t] - v;
        if (base + t < nbuck) { boff[base + t] = excl; gcur[base + t] = excl; }
        __syncthreads();
        if (t == 0) carry += sm[255];
        __syncthreads();
    }
    if (t == 0) boff[nbuck] = total;
}

// bucket scatter with per-block LDS aggregation:
// one global atomic per (block,bucket); writes land in ~64B runs.
// rec = (meta = dstlocal<<17 | src, ea bits)
__global__ void k_bscatter(const int* __restrict__ src, const int* __restrict__ dst,
                           const float* __restrict__ ea, int* __restrict__ gcur,
                           uint2* __restrict__ rec, int E, int nbuck) {
    __shared__ int lcnt[MAXBUCK];
    __shared__ int lbase[MAXBUCK];
    const int nb = gridDim.x;
    const long c0 = (long)E * blockIdx.x / nb;
    const long c1 = (long)E * (blockIdx.x + 1) / nb;
    for (int i = threadIdx.x; i < nbuck; i += blockDim.x) lcnt[i] = 0;
    __syncthreads();
    for (long e = c0 + threadIdx.x; e < c1; e += blockDim.x)
        atomicAdd(&lcnt[dst[e] >> 6], 1);
    __syncthreads();
    for (int i = threadIdx.x; i < nbuck; i += blockDim.x) {
        int c = lcnt[i];
        lbase[i] = c ? atomicAdd(&gcur[i], c) : 0;
    }
    __syncthreads();
    for (int i = threadIdx.x; i < nbuck; i += blockDim.x) lcnt[i] = 0;
    __syncthreads();
    for (long e = c0 + threadIdx.x; e < c1; e += blockDim.x) {
        int d = dst[e];
        int b = d >> 6;
        int rank = atomicAdd(&lcnt[b], 1);
        unsigned meta = ((unsigned)(d & 63) << 17) | (unsigned)src[e];
        rec[lbase[b] + rank] = make_uint2(meta, __float_as_uint(ea[e]));
    }
}

// ---------------- per-layer kernels ----------------

// layer-0: M = x@Wx0 + p@Wp0, fp16 output
__global__ void k_node_gemm5(const float* __restrict__ h, const float* __restrict__ p,
                             const float* __restrict__ Wx, const float* __restrict__ Wp,
                             __half* __restrict__ Mh, int n_nodes) {
    __shared__ float sWx[5 * 32];
    __shared__ float sWp[96];
    for (int i = threadIdx.x; i < 5 * 32; i += blockDim.x) sWx[i] = Wx[i];
    if (threadIdx.x < 96) sWp[threadIdx.x] = Wp[threadIdx.x];
    __syncthreads();
    const int k = threadIdx.x & 31;
    int n = blockIdx.x * (blockDim.x >> 5) + (threadIdx.x >> 5);
    if (n >= n_nodes) return;
    float hv = (k < 5) ? h[n * 5 + k] : 0.0f;
    float pv = (k < 3) ? p[n * 3 + k] : 0.0f;
    float acc = 0.0f;
    #pragma unroll
    for (int j = 0; j < 5; ++j) acc = fmaf(__shfl(hv, j, 32), sWx[j * 32 + k], acc);
    #pragma unroll
    for (int j = 0; j < 3; ++j) acc = fmaf(__shfl(pv, j, 32), sWp[j * 32 + k], acc);
    Mh[n * 32 + k] = __float2half(acc);
}

// bucket-parallel edge message: sim[n][k] = sum tanh(M[src][k] + Cn[n][k] + ea*We[k])
__global__ void k_bedge(const __half* __restrict__ Mh, const float* __restrict__ p,
                        const int* __restrict__ boff, const uint2* __restrict__ rec,
                        const float* __restrict__ Wp, const float* __restrict__ We,
                        const float* __restrict__ bias,
                        __half* __restrict__ simh, int N) {
    __shared__ float sAcc[BN * 32];
    __shared__ float sCn[BN * 32];
    __shared__ float sP[BN * 3];
    const int b = blockIdx.x;
    const int n0 = b * BN;
    const int nn = min(BN, N - n0);
    const int tid = threadIdx.x, k = tid & 31, g = tid >> 5;

    for (int i = tid; i < BN * 32; i += 256) sAcc[i] = 0.0f;
    if (tid < nn * 3) sP[tid] = p[n0 * 3 + tid];
    __syncthreads();

    float we = We[k];
    float bk = bias[k];
    float wp0 = Wp[k], wp1 = Wp[32 + k], wp2 = Wp[64 + k];
    #pragma unroll
    for (int it = 0; it < 8; ++it) {
        int nl = g * 8 + it;
        if (nl < nn)
            sCn[nl * 32 + k] = bk - (sP[nl * 3] * wp0 + sP[nl * 3 + 1] * wp1
                                     + sP[nl * 3 + 2] * wp2);
    }
    __syncthreads();

    int e0 = boff[b], e1 = boff[b + 1];
    int tot = e1 - e0, per = (tot + 7) >> 3;
    int ge0 = e0 + g * per;
    int ge1 = min(e1, ge0 + per);
    for (int base = ge0; base < ge1; base += 32) {
        int m = min(32, ge1 - base);
        uint2 r = (k < m) ? rec[base + k] : make_uint2(0u, 0u);
        for (int j = 0; j < m; j += 4) {
            int me0 = __shfl((int)r.x, j, 32);
            int me1 = __shfl((int)r.x, j + 1, 32);
            int me2 = __shfl((int)r.x, j + 2, 32);
            int me3 = __shfl((int)r.x, j + 3, 32);
            float a0 = __uint_as_float((unsigned)__shfl((int)r.y, j, 32));
            float a1 = __uint_as_float((unsigned)__shfl((int)r.y, j + 1, 32));
            float a2 = __uint_as_float((unsigned)__shfl((int)r.y, j + 2, 32));
            float a3 = __uint_as_float((unsigned)__shfl((int)r.y, j + 3, 32));
            float m0 = __half2float(Mh[(me0 & 0x1FFFF) * 32 + k]);   // 4 gathers in flight
            float m1 = __half2float(Mh[(me1 & 0x1FFFF) * 32 + k]);
            float m2 = __half2float(Mh[(me2 & 0x1FFFF) * 32 + k]);
            float m3 = __half2float(Mh[(me3 & 0x1FFFF) * 32 + k]);
            float t0 = tanh_fast(fmaf(a0, we, sCn[(me0 >> 17) * 32 + k]) + m0);
            float t1 = tanh_fast(fmaf(a1, we, sCn[(me1 >> 17) * 32 + k]) + m1);
            float t2 = tanh_fast(fmaf(a2, we, sCn[(me2 >> 17) * 32 + k]) + m2);
            float t3 = tanh_fast(fmaf(a3, we, sCn[(me3 >> 17) * 32 + k]) + m3);
            atomicAdd(&sAcc[(me0 >> 17) * 32 + k], t0);
            if (j + 1 < m) atomicAdd(&sAcc[(me1 >> 17) * 32 + k], t1);
            if (j + 2 < m) atomicAdd(&sAcc[(me2 >> 17) * 32 + k], t2);
            if (j + 3 < m) atomicAdd(&sAcc[(me3 >> 17) * 32 + k], t3);
        }
    }
    __syncthreads();
    for (int i = tid; i < nn * 32; i += 256)
        simh[n0 * 32 + i] = __float2half(sAcc[i]);
}

// bucket-parallel propagate (+ optional fused next-layer GEMM)
template <int FUSE>
__global__ void k_bprop(const __half* __restrict__ simh, const int* __restrict__ boff,
                        const uint2* __restrict__ rec, const float* __restrict__ p,
                        const float* __restrict__ Wx, const float* __restrict__ Wp,
                        __half* __restrict__ outMh, float* __restrict__ outF, int N) {
    __shared__ float sAcc[BN * 32];
    __shared__ float sWx[1024];
    __shared__ float sP[BN * 3];
    const int b = blockIdx.x;
    const int n0 = b * BN;
    const int nn = min(BN, N - n0);
    const int tid = threadIdx.x, k = tid & 31, g = tid >> 5;

    for (int i = tid; i < BN * 32; i += 256) sAcc[i] = 0.0f;
    if (FUSE) {
        for (int i = tid; i < 1024; i += 256) sWx[i] = Wx[i];
        if (tid < nn * 3) sP[tid] = p[n0 * 3 + tid];
    }
    __syncthreads();

    int e0 = boff[b], e1 = boff[b + 1];
    int tot = e1 - e0, per = (tot + 7) >> 3;
    int ge0 = e0 + g * per;
    int ge1 = min(e1, ge0 + per);
    for (int base = ge0; base < ge1; base += 32) {
        int m = min(32, ge1 - base);
        uint2 r = (k < m) ? rec[base + k] : make_uint2(0u, 0u);
        for (int j = 0; j < m; j += 4) {
            int me0 = __shfl((int)r.x, j, 32);
            int me1 = __shfl((int)r.x, j + 1, 32);
            int me2 = __shfl((int)r.x, j + 2, 32);
            int me3 = __shfl((int)r.x, j + 3, 32);
            float v0 = __half2float(simh[(me0 & 0x1FFFF) * 32 + k]);
            float v1 = __half2float(simh[(me1 & 0x1FFFF) * 32 + k]);
            float v2 = __half2float(simh[(me2 & 0x1FFFF) * 32 + k]);
            float v3 = __half2float(simh[(me3 & 0x1FFFF) * 32 + k]);
            atomicAdd(&sAcc[(me0 >> 17) * 32 + k], v0);
            if (j + 1 < m) atomicAdd(&sAcc[(me1 >> 17) * 32 + k], v1);
            if (j + 2 < m) atomicAdd(&sAcc[(me2 >> 17) * 32 + k], v2);
            if (j + 3 < m) atomicAdd(&sAcc[(me3 >> 17) * 32 + k], v3);
        }
    }
    __syncthreads();

    if (!FUSE) {
        for (int i = tid; i < nn * 32; i += 256) outF[n0 * 32 + i] = sAcc[i];
        return;
    }
    float wp0 = Wp[k], wp1 = Wp[32 + k], wp2 = Wp[64 + k];
    #pragma unroll
    for (int it = 0; it < 8; ++it) {
        int nl = g * 8 + it;
        if (nl >= nn) break;
        float mm = sP[nl * 3] * wp0 + sP[nl * 3 + 1] * wp1 + sP[nl * 3 + 2] * wp2;
        #pragma unroll
        for (int j = 0; j < 32; ++j)
            mm = fmaf(sAcc[nl * 32 + j], sWx[j * 32 + k], mm);   // LDS broadcast read
        outMh[(n0 + nl) * 32 + k] = __float2half(mm);
    }
}

// ---------------- pooling + head ----------------

__global__ void k_pool(const float* __restrict__ h, const int* __restrict__ batch,
                       const float* __restrict__ Wh, const float* __restrict__ bh,
                       float* __restrict__ out, int n_nodes, int n_graphs) {
    __shared__ int sLo, sHi;
    __shared__ float red[256];
    int g = blockIdx.x;
    if (threadIdx.x == 0) {
        int lo = 0, hi = n_nodes;
        while (lo < hi) { int m = (lo + hi) >> 1; if (batch[m] < g) lo = m + 1; else hi = m; }
        sLo = lo;
        lo = 0; hi = n_nodes; int g1 = g + 1;
        while (lo < hi) { int m = (lo + hi) >> 1; if (batch[m] < g1) lo = m + 1; else hi = m; }
        sHi = lo;
    }
    __syncthreads();
    int lo = sLo, hi = sHi;
    int k = threadIdx.x & 31, r = threadIdx.x >> 5;
    float acc = 0.0f;
    for (int n = lo + r; n < hi; n += 8) acc += h[n * 32 + k];
    red[threadIdx.x] = acc;
    __syncthreads();
    if (threadIdx.x < 32) {
        float s = 0.0f;
        #pragma unroll
        for (int r2 = 0; r2 < 8; ++r2) s += red[r2 * 32 + k];
        float c = (float)(hi - lo);
        float rep = s / fmaxf(c, 1.0f);
        out[n_graphs + g * 32 + k] = rep;
        float t = rep * Wh[k];
        #pragma unroll
        for (int d = 16; d > 0; d >>= 1) t += __shfl_down(t, d, 32);
        if (k == 0) out[g] = t + bh[0];
    }
}

// ---------------- launch ----------------

extern "C" void kernel_launch(void* const* d_in, const int* in_sizes, int n_in,
                              void* d_out, int out_size, void* d_ws, size_t ws_size,
                              hipStream_t stream) {
    const float* x   = (const float*)d_in[0];
    const float* p   = (const float*)d_in[1];
    const float* ea  = (const float*)d_in[2];
    const float* Wx0 = (const float*)d_in[3];
    const float* Wx1 = (const float*)d_in[4];
    const float* Wx2 = (const float*)d_in[5];
    const float* Wp0 = (const float*)d_in[6];
    const float* Wp1 = (const float*)d_in[7];
    const float* Wp2 = (const float*)d_in[8];
    const float* We0 = (const float*)d_in[9];
    const float* We1 = (const float*)d_in[10];
    const float* We2 = (const float*)d_in[11];
    const float* b0  = (const float*)d_in[12];
    const float* b1  = (const float*)d_in[13];
    const float* b2  = (const float*)d_in[14];
    const float* Wh  = (const float*)d_in[15];
    const float* bh  = (const float*)d_in[16];
    const int* edge_index = (const int*)d_in[17];
    const int* batch      = (const int*)d_in[18];

    const int N = in_sizes[0] / 5;
    const int E = in_sizes[17] / 2;
    const int G = out_size / 33;
    const int nbuck = (N + BN - 1) / BN;     // 1563 for N=100000 (<= MAXBUCK)

    const int* srcp = edge_index;
    const int* dstp = edge_index + E;

    char* w = (char*)d_ws;
    auto alloc = [&](size_t bytes) -> void* {
        void* r = (void*)w;
        w += (bytes + 255) & ~(size_t)255;
        return r;
    };
    int*    bcnt = (int*)alloc((size_t)nbuck * 4);
    int*    boff = (int*)alloc((size_t)(nbuck + 1) * 4);
    int*    gcur = (int*)alloc((size_t)nbuck * 4);
    uint2*  rec  = (uint2*)alloc((size_t)E * 8);
    __half* Mh   = (__half*)alloc((size_t)N * K_DIM * 2);
    __half* simh = (__half*)alloc((size_t)N * K_DIM * 2);
    float*  hB   = (float*)alloc((size_t)N * K_DIM * 4);

    // bucket build
    (void)hipMemsetAsync(bcnt, 0, (size_t)nbuck * 4, stream);
    k_bcnt<<<256, 256, 0, stream>>>(dstp, bcnt, E, nbuck);
    k_bscan<<<1, 256, 0, stream>>>(bcnt, boff, gcur, nbuck, E);
    k_bscatter<<<256, 256, 0, stream>>>(srcp, dstp, ea, gcur, rec, E, nbuck);

    // layer 0
    k_node_gemm5<<<(N + 7) / 8, 256, 0, stream>>>(x, p, Wx0, Wp0, Mh, N);
    k_bedge<<<nbuck, 256, 0, stream>>>(Mh, p, boff, rec, Wp0, We0, b0, simh, N);
    k_bprop<1><<<nbuck, 256, 0, stream>>>(simh, boff, rec, p, Wx1, Wp1, Mh, nullptr, N);
    // layer 1
    k_bedge<<<nbuck, 256, 0, stream>>>(Mh, p, boff, rec, Wp1, We1, b1, simh, N);
    k_bprop<1><<<nbuck, 256, 0, stream>>>(simh, boff, rec, p, Wx2, Wp2, Mh, nullptr, N);
    // layer 2
    k_bedge<<<nbuck, 256, 0, stream>>>(Mh, p, boff, rec, Wp2, We2, b2, simh, N);
    k_bprop<0><<<nbuck, 256, 0, stream>>>(simh, boff, rec, p, nullptr, nullptr, nullptr, hB, N);

    // pool + head
    k_pool<<<G, 256, 0, stream>>>(hB, batch, Wh, bh, (float*)d_out, N, G);
}

// Round 7
// 549.584 us; speedup vs baseline: 7.0330x; 7.0330x over previous
//
#include <hip/hip_runtime.h>
#include <hip/hip_fp16.h>

#define K_DIM 32
#define BN 64               // nodes per bucket
#define MAXBUCK 2048        // LDS histogram capacity (nbuck <= 2048)
#define CAP 6912            // per-bucket record staging (mean 2048, +108 sigma)

__device__ __forceinline__ float tanh_fast(float x) {
    float e = __expf(2.0f * x);
    return 1.0f - 2.0f / (e + 1.0f);
}

// ---------------- bucket build ----------------

__global__ void k_bcnt(const int* __restrict__ dst, int* __restrict__ bcnt,
                       int E, int nbuck) {
    __shared__ int h[MAXBUCK];
    for (int i = threadIdx.x; i < nbuck; i += blockDim.x) h[i] = 0;
    __syncthreads();
    for (int e = blockIdx.x * blockDim.x + threadIdx.x; e < E; e += gridDim.x * blockDim.x)
        atomicAdd(&h[dst[e] >> 6], 1);
    __syncthreads();
    for (int i = threadIdx.x; i < nbuck; i += blockDim.x)
        if (h[i]) atomicAdd(&bcnt[i], h[i]);
}

__global__ void k_bscan(const int* __restrict__ bcnt, int* __restrict__ boff,
                        int* __restrict__ gcur, int nbuck, int total) {
    __shared__ int sm[256];
    __shared__ int carry;
    int t = threadIdx.x;
    if (t == 0) carry = 0;
    __syncthreads();
    for (int base = 0; base < nbuck; base += 256) {
        int v = (base + t < nbuck) ? bcnt[base + t] : 0;
        sm[t] = v;
        __syncthreads();
        #pragma unroll
        for (int d = 1; d < 256; d <<= 1) {
            int tv = (t >= d) ? sm[t - d] : 0;
            __syncthreads();
            sm[t] += tv;
            __syncthreads();
        }
        int excl = carry + sm[t] - v;
        if (base + t < nbuck) { boff[base + t] = excl; gcur[base + t] = excl; }
        __syncthreads();
        if (t == 0) carry += sm[255];
        __syncthreads();
    }
    if (t == 0) boff[nbuck] = total;
}

// bucket scatter with per-block LDS rank aggregation
// rec = (meta = dstlocal<<17 | src, ea bits)
__global__ void k_bscatter(const int* __restrict__ src, const int* __restrict__ dst,
                           const float* __restrict__ ea, int* __restrict__ gcur,
                           uint2* __restrict__ rec, int E, int nbuck) {
    __shared__ int lcnt[MAXBUCK];
    __shared__ int lbase[MAXBUCK];
    const int nb = gridDim.x;
    const long c0 = (long)E * blockIdx.x / nb;
    const long c1 = (long)E * (blockIdx.x + 1) / nb;
    for (int i = threadIdx.x; i < nbuck; i += blockDim.x) lcnt[i] = 0;
    __syncthreads();
    for (long e = c0 + threadIdx.x; e < c1; e += blockDim.x)
        atomicAdd(&lcnt[dst[e] >> 6], 1);
    __syncthreads();
    for (int i = threadIdx.x; i < nbuck; i += blockDim.x) {
        int c = lcnt[i];
        lbase[i] = c ? atomicAdd(&gcur[i], c) : 0;
    }
    __syncthreads();
    for (int i = threadIdx.x; i < nbuck; i += blockDim.x) lcnt[i] = 0;
    __syncthreads();
    for (long e = c0 + threadIdx.x; e < c1; e += blockDim.x) {
        int d = dst[e];
        int b = d >> 6;
        int rank = atomicAdd(&lcnt[b], 1);
        unsigned meta = ((unsigned)(d & 63) << 17) | (unsigned)src[e];
        rec[lbase[b] + rank] = make_uint2(meta, __float_as_uint(ea[e]));
    }
}

// within-bucket sort by node (in LDS, in-place on rec) + per-node off[]
__global__ void k_blocal(uint2* __restrict__ rec, const int* __restrict__ boff,
                         int* __restrict__ off, int N, int E) {
    __shared__ uint2 sB[CAP];
    __shared__ int cnt[BN];
    __shared__ int base[BN];
    const int b = blockIdx.x;
    const int tid = threadIdx.x;
    int e0 = boff[b], e1 = boff[b + 1];
    int tot = e1 - e0;
    if (tid < BN) cnt[tid] = 0;
    __syncthreads();
    for (int i = tid; i < tot; i += 256)
        atomicAdd(&cnt[rec[e0 + i].x >> 17], 1);
    __syncthreads();
    if (tid == 0) {
        int run = 0;
        #pragma unroll 8
        for (int i = 0; i < BN; ++i) { base[i] = run; run += cnt[i]; }
    }
    __syncthreads();
    int n = b * BN + tid;
    if (tid < BN && n < N) off[n] = e0 + base[tid];
    if (b == 0 && tid == 64) off[N] = E;
    if (tid < BN) cnt[tid] = 0;
    __syncthreads();
    for (int i = tid; i < tot; i += 256) {
        uint2 r = rec[e0 + i];
        int dl = r.x >> 17;
        int rank = atomicAdd(&cnt[dl], 1);
        sB[base[dl] + rank] = make_uint2(r.x & 0x1FFFFu, r.y);  // (src, ea)
    }
    __syncthreads();
    for (int i = tid; i < tot; i += 256) rec[e0 + i] = sB[i];
}

// ---------------- per-layer kernels ----------------

// layer-0: M = x@Wx0 + p@Wp0, fp16 output
__global__ void k_node_gemm5(const float* __restrict__ h, const float* __restrict__ p,
                             const float* __restrict__ Wx, const float* __restrict__ Wp,
                             __half* __restrict__ Mh, int n_nodes) {
    __shared__ float sWx[5 * 32];
    __shared__ float sWp[96];
    for (int i = threadIdx.x; i < 5 * 32; i += blockDim.x) sWx[i] = Wx[i];
    if (threadIdx.x < 96) sWp[threadIdx.x] = Wp[threadIdx.x];
    __syncthreads();
    const int k = threadIdx.x & 31;
    int n = blockIdx.x * (blockDim.x >> 5) + (threadIdx.x >> 5);
    if (n >= n_nodes) return;
    float hv = (k < 5) ? h[n * 5 + k] : 0.0f;
    float pv = (k < 3) ? p[n * 3 + k] : 0.0f;
    float acc = 0.0f;
    #pragma unroll
    for (int j = 0; j < 5; ++j) acc = fmaf(__shfl(hv, j, 32), sWx[j * 32 + k], acc);
    #pragma unroll
    for (int j = 0; j < 3; ++j) acc = fmaf(__shfl(pv, j, 32), sWp[j * 32 + k], acc);
    Mh[n * 32 + k] = __float2half(acc);
}

// sim[n][k] = sum_{e: dst==n} tanh(M[src_e][k] + cnst_n[k] + ea_e*We[k])
// 32-lane group per node; 8 independent fp16 row-gathers in flight.
__global__ void k_edge_msg(const __half* __restrict__ Mh, const float* __restrict__ p,
                           const int* __restrict__ off, const uint2* __restrict__ rec,
                           const float* __restrict__ Wp, const float* __restrict__ We,
                           const float* __restrict__ b,
                           __half* __restrict__ simh, int N) {
    const int k = threadIdx.x & 31;
    int n = blockIdx.x * (blockDim.x >> 5) + (threadIdx.x >> 5);
    if (n >= N) return;

    float pn = (k < 3) ? p[n * 3 + k] : 0.0f;
    float cnst = b[k] - (__shfl(pn, 0, 32) * Wp[k] + __shfl(pn, 1, 32) * Wp[32 + k]
                         + __shfl(pn, 2, 32) * Wp[64 + k]);
    float we = We[k];
    float acc = 0.0f;

    int e0 = off[n], e1 = off[n + 1];
    for (int base = e0; base < e1; base += 32) {
        int m = min(32, e1 - base);
        uint2 r = (k < m) ? rec[base + k] : make_uint2(0u, 0u);   // lane>=m -> src 0 (safe)
        for (int j = 0; j < m; j += 8) {
            float t[8];
            #pragma unroll
            for (int u = 0; u < 8; ++u) {
                int s = __shfl((int)r.x, j + u, 32);
                float a = __uint_as_float((unsigned)__shfl((int)r.y, j + u, 32));
                float mv = __half2float(Mh[s * 32 + k]);
                t[u] = tanh_fast(fmaf(a, we, cnst) + mv);
            }
            #pragma unroll
            for (int u = 0; u < 8; ++u)
                if (j + u < m) acc += t[u];
        }
    }
    simh[n * 32 + k] = __float2half(acc);
}

// h_next[n] = sum over in-edges of sim[src]; optionally fused next-layer GEMM
template <int FUSE>
__global__ void k_prop_gemm(const __half* __restrict__ simh, const int* __restrict__ off,
                            const uint2* __restrict__ rec, const float* __restrict__ p,
                            const float* __restrict__ Wx, const float* __restrict__ Wp,
                            __half* __restrict__ outMh, float* __restrict__ outF,
                            int N) {
    __shared__ float sWx[1024];
    if (FUSE) {
        for (int i = threadIdx.x; i < 1024; i += blockDim.x) sWx[i] = Wx[i];
        __syncthreads();
    }
    const int k = threadIdx.x & 31;
    int n = blockIdx.x * (blockDim.x >> 5) + (threadIdx.x >> 5);
    if (n >= N) return;

    float acc = 0.0f;
    int e0 = off[n], e1 = off[n + 1];
    for (int base = e0; base < e1; base += 32) {
        int m = min(32, e1 - base);
        unsigned sv = (k < m) ? rec[base + k].x : 0u;
        for (int j = 0; j < m; j += 8) {
            float t[8];
            #pragma unroll
            for (int u = 0; u < 8; ++u) {
                int s = __shfl((int)sv, j + u, 32);
                t[u] = __half2float(simh[s * 32 + k]);
            }
            #pragma unroll
            for (int u = 0; u < 8; ++u)
                if (j + u < m) acc += t[u];
        }
    }

    if (!FUSE) { outF[n * 32 + k] = acc; return; }
    float mm = 0.0f;
    #pragma unroll
    for (int j = 0; j < 32; ++j) mm = fmaf(__shfl(acc, j, 32), sWx[j * 32 + k], mm);
    float pv = (k < 3) ? p[n * 3 + k] : 0.0f;
    mm = fmaf(__shfl(pv, 0, 32), Wp[k], mm);
    mm = fmaf(__shfl(pv, 1, 32), Wp[32 + k], mm);
    mm = fmaf(__shfl(pv, 2, 32), Wp[64 + k], mm);
    outMh[n * 32 + k] = __float2half(mm);
}

// ---------------- pooling + head ----------------

__global__ void k_pool(const float* __restrict__ h, const int* __restrict__ batch,
                       const float* __restrict__ Wh, const float* __restrict__ bh,
                       float* __restrict__ out, int n_nodes, int n_graphs) {
    __shared__ int sLo, sHi;
    __shared__ float red[256];
    int g = blockIdx.x;
    if (threadIdx.x == 0) {
        int lo = 0, hi = n_nodes;
        while (lo < hi) { int m = (lo + hi) >> 1; if (batch[m] < g) lo = m + 1; else hi = m; }
        sLo = lo;
        lo = 0; hi = n_nodes; int g1 = g + 1;
        while (lo < hi) { int m = (lo + hi) >> 1; if (batch[m] < g1) lo = m + 1; else hi = m; }
        sHi = lo;
    }
    __syncthreads();
    int lo = sLo, hi = sHi;
    int k = threadIdx.x & 31, r = threadIdx.x >> 5;
    float acc = 0.0f;
    for (int n = lo + r; n < hi; n += 8) acc += h[n * 32 + k];
    red[threadIdx.x] = acc;
    __syncthreads();
    if (threadIdx.x < 32) {
        float s = 0.0f;
        #pragma unroll
        for (int r2 = 0; r2 < 8; ++r2) s += red[r2 * 32 + k];
        float c = (float)(hi - lo);
        float rep = s / fmaxf(c, 1.0f);
        out[n_graphs + g * 32 + k] = rep;
        float t = rep * Wh[k];
        #pragma unroll
        for (int d = 16; d > 0; d >>= 1) t += __shfl_down(t, d, 32);
        if (k == 0) out[g] = t + bh[0];
    }
}

// ---------------- launch ----------------

extern "C" void kernel_launch(void* const* d_in, const int* in_sizes, int n_in,
                              void* d_out, int out_size, void* d_ws, size_t ws_size,
                              hipStream_t stream) {
    const float* x   = (const float*)d_in[0];
    const float* p   = (const float*)d_in[1];
    const float* ea  = (const float*)d_in[2];
    const float* Wx0 = (const float*)d_in[3];
    const float* Wx1 = (const float*)d_in[4];
    const float* Wx2 = (const float*)d_in[5];
    const float* Wp0 = (const float*)d_in[6];
    const float* Wp1 = (const float*)d_in[7];
    const float* Wp2 = (const float*)d_in[8];
    const float* We0 = (const float*)d_in[9];
    const float* We1 = (const float*)d_in[10];
    const float* We2 = (const float*)d_in[11];
    const float* b0  = (const float*)d_in[12];
    const float* b1  = (const float*)d_in[13];
    const float* b2  = (const float*)d_in[14];
    const float* Wh  = (const float*)d_in[15];
    const float* bh  = (const float*)d_in[16];
    const int* edge_index = (const int*)d_in[17];
    const int* batch      = (const int*)d_in[18];

    const int N = in_sizes[0] / 5;
    const int E = in_sizes[17] / 2;
    const int G = out_size / 33;
    const int nbuck = (N + BN - 1) / BN;     // 1563 for N=100000

    const int* srcp = edge_index;
    const int* dstp = edge_index + E;

    char* w = (char*)d_ws;
    auto alloc = [&](size_t bytes) -> void* {
        void* r = (void*)w;
        w += (bytes + 255) & ~(size_t)255;
        return r;
    };
    int*    bcnt = (int*)alloc((size_t)nbuck * 4);
    int*    boff = (int*)alloc((size_t)(nbuck + 1) * 4);
    int*    gcur = (int*)alloc((size_t)nbuck * 4);
    int*    off  = (int*)alloc((size_t)(N + 1) * 4);
    uint2*  rec  = (uint2*)alloc((size_t)E * 8);
    __half* Mh   = (__half*)alloc((size_t)N * K_DIM * 2);
    __half* simh = (__half*)alloc((size_t)N * K_DIM * 2);
    float*  hB   = (float*)alloc((size_t)N * K_DIM * 4);

    // build: bucket sort -> within-bucket node sort -> per-node CSR
    (void)hipMemsetAsync(bcnt, 0, (size_t)nbuck * 4, stream);
    k_bcnt<<<256, 256, 0, stream>>>(dstp, bcnt, E, nbuck);
    k_bscan<<<1, 256, 0, stream>>>(bcnt, boff, gcur, nbuck, E);
    k_bscatter<<<256, 256, 0, stream>>>(srcp, dstp, ea, gcur, rec, E, nbuck);
    k_blocal<<<nbuck, 256, 0, stream>>>(rec, boff, off, N, E);

    const int NB = (N + 7) / 8;   // 8 node-groups (32 lanes) per 256-thread block

    // layer 0
    k_node_gemm5<<<NB, 256, 0, stream>>>(x, p, Wx0, Wp0, Mh, N);
    k_edge_msg<<<NB, 256, 0, stream>>>(Mh, p, off, rec, Wp0, We0, b0, simh, N);
    k_prop_gemm<1><<<NB, 256, 0, stream>>>(simh, off, rec, p, Wx1, Wp1, Mh, nullptr, N);
    // layer 1
    k_edge_msg<<<NB, 256, 0, stream>>>(Mh, p, off, rec, Wp1, We1, b1, simh, N);
    k_prop_gemm<1><<<NB, 256, 0, stream>>>(simh, off, rec, p, Wx2, Wp2, Mh, nullptr, N);
    // layer 2
    k_edge_msg<<<NB, 256, 0, stream>>>(Mh, p, off, rec, Wp2, We2, b2, simh, N);
    k_prop_gemm<0><<<NB, 256, 0, stream>>>(simh, off, rec, p, nullptr, nullptr, nullptr, hB, N);

    // pool + head
    k_pool<<<G, 256, 0, stream>>>(hB, batch, Wh, bh, (float*)d_out, N, G);
}